// Round 7
// baseline (284.710 us; speedup 1.0000x reference)
//
#include <hip/hip_runtime.h>

typedef unsigned short u16;
typedef __attribute__((ext_vector_type(8))) short shortx8;
typedef __attribute__((ext_vector_type(4))) float floatx4;
typedef __attribute__((ext_vector_type(2))) unsigned uintx2;

#define GLD16(gp, lp) __builtin_amdgcn_global_load_lds( \
    (__attribute__((address_space(1))) void*)(gp), \
    (__attribute__((address_space(3))) void*)(lp), 16, 0, 0)

__device__ __forceinline__ u16 f2bf(float f) {
  union { float f; unsigned u; } v; v.f = f;
  unsigned r = v.u + 0x7FFFu + ((v.u >> 16) & 1u);
  return (u16)(r >> 16);
}

// pack two f32 -> bf16x2 in one u32 (low = a, high = b)
__device__ __forceinline__ unsigned pkbf(float a, float b) {
#if __has_builtin(__builtin_amdgcn_cvt_pk_bf16_f32)
  auto r = __builtin_amdgcn_cvt_pk_bf16_f32(a, b);
  return __builtin_bit_cast(unsigned, r);
#else
  union { float f; unsigned u; } x, y; x.f = a; y.f = b;
  return __builtin_amdgcn_perm(y.u + 0x8000u, x.u + 0x8000u, 0x07060302u);
#endif
}

// ---------------- prep: cast x -> bf16  +  transpose-cast 4 weights ----------------
__global__ __launch_bounds__(256) void prep_kernel(const float* __restrict__ x,
                                                   u16* __restrict__ xb,
                                                   const float* __restrict__ Wq,
                                                   const float* __restrict__ Wk,
                                                   const float* __restrict__ Wv,
                                                   const float* __restrict__ Wo,
                                                   u16* __restrict__ Wt) {
  __shared__ u16 tile[32][33];
  int bid = blockIdx.x;
  int tid = threadIdx.x;
  if (bid < 4096) {
    int i = bid * 256 + tid;
    float4 v = ((const float4*)x)[i];
    uintx2 o;
    o.x = pkbf(v.x, v.y);
    o.y = pkbf(v.z, v.w);
    ((uintx2*)xb)[i] = o;
  } else {
    int block = bid - 4096;
    int mat = block >> 10;
    int rem = block & 1023;
    const float* W = (mat == 0) ? Wq : (mat == 1) ? Wk : (mat == 2) ? Wv : Wo;
    u16* dst = Wt + (size_t)mat * 1024 * 1024;
    int n0 = (rem & 31) * 32, k0 = (rem >> 5) * 32;
    int tx = tid & 31, ty = tid >> 5;
    for (int i = 0; i < 4; ++i)
      tile[ty + i * 8][tx] = f2bf(W[(size_t)(k0 + ty + i * 8) * 1024 + n0 + tx]);
    __syncthreads();
    for (int i = 0; i < 4; ++i)
      dst[(size_t)(n0 + ty + i * 8) * 1024 + k0 + tx] = tile[tx][ty + i * 8];
  }
}

// ---------------- shared GEMM core: C[128x128] += A[M,K] * Bt[N,K]^T ----------------
__device__ __forceinline__ void gemm_tile_core(const u16* __restrict__ A,
                                               const u16* __restrict__ Bt,
                                               int m0, int n0,
                                               u16* As, u16* Bs,
                                               floatx4 (&acc)[4][4]) {
  const int tid = threadIdx.x;
  const int wave = tid >> 6, lane = tid & 63;
  const int lrow = lane >> 4, lcol = lane & 15;
  const int wm = wave >> 1, wn = wave & 1;

  for (int mi = 0; mi < 4; ++mi)
    for (int ni = 0; ni < 4; ++ni)
      acc[mi][ni] = (floatx4){0.f, 0.f, 0.f, 0.f};

  const u16* ap[4];
  const u16* bp[4];
  for (int l = 0; l < 4; ++l) {
    int g = (l * 4 + wave) * 64 + lane;
    int r = g >> 3, c = g & 7;
    int cc = (c ^ (r & 7)) * 8;
    ap[l] = A + (size_t)(m0 + r) * 1024 + cc;
    bp[l] = Bt + (size_t)(n0 + r) * 1024 + cc;
  }

  for (int k0 = 0; k0 < 1024; k0 += 64) {
    __syncthreads();
    for (int l = 0; l < 4; ++l) {
      GLD16(ap[l], As + (l * 4 + wave) * 512);
      GLD16(bp[l], Bs + (l * 4 + wave) * 512);
      ap[l] += 64; bp[l] += 64;
    }
    __syncthreads();
    for (int kk = 0; kk < 2; ++kk) {
      shortx8 af[4], bf[4];
      for (int mi = 0; mi < 4; ++mi) {
        int row = wm * 64 + mi * 16 + lcol;
        int gr = (kk * 4 + lrow) ^ (row & 7);
        af[mi] = *(const shortx8*)&As[row * 64 + gr * 8];
      }
      for (int ni = 0; ni < 4; ++ni) {
        int row = wn * 64 + ni * 16 + lcol;
        int gr = (kk * 4 + lrow) ^ (row & 7);
        bf[ni] = *(const shortx8*)&Bs[row * 64 + gr * 8];
      }
      for (int mi = 0; mi < 4; ++mi)
        for (int ni = 0; ni < 4; ++ni)
          acc[mi][ni] = __builtin_amdgcn_mfma_f32_16x16x32_bf16(af[mi], bf[ni], acc[mi][ni], 0, 0, 0);
    }
  }
}

// ---------------- fused QKV projection ----------------
// Q is pre-scaled by log2(e)/sqrt(HD). Q/K epilogue transposes through the dead
// staging LDS to emit packed 16B stores instead of 64 scalar 2B stores.
__global__ __launch_bounds__(256) void qkv_gemm(const u16* __restrict__ xb,
                                                const u16* __restrict__ Wt,
                                                const float* __restrict__ bq,
                                                const float* __restrict__ bk,
                                                const float* __restrict__ bv,
                                                u16* __restrict__ Qh,
                                                u16* __restrict__ Kh,
                                                u16* __restrict__ Vth) {
  __shared__ u16 sbuf[128 * 128];   // As = first half, Bs = second half; reused as C-tile
  u16* As = sbuf;
  u16* Bs = sbuf + 128 * 64;
  int m0 = blockIdx.x * 128;
  int mat = blockIdx.y >> 3;
  int n0 = (blockIdx.y & 7) * 128;
  floatx4 acc[4][4];
  gemm_tile_core(xb, Wt + (size_t)mat * 1024 * 1024, m0, n0, As, Bs, acc);

  const float* bias = (mat == 0) ? bq : (mat == 1) ? bk : bv;
  const int tid = threadIdx.x;
  const int wave = tid >> 6, lane = tid & 63;
  const int lrow = lane >> 4, lcol = lane & 15;
  const int wm = wave >> 1, wn = wave & 1;
  const float qscale = 0.18033688011f;  // log2(e)/8

  if (mat < 2) {
    u16* dst = (mat == 0) ? Qh : Kh;
    float sc = (mat == 0) ? qscale : 1.0f;
    __syncthreads();  // staging LDS now dead; reuse as 128x128 C tile
    for (int mi = 0; mi < 4; ++mi) {
      int mb = wm * 64 + mi * 16 + lrow * 4;
      for (int ni = 0; ni < 4; ++ni) {
        int n = wn * 64 + ni * 16 + lcol;
        float bval = bias[n0 + n];
        for (int r = 0; r < 4; ++r) {
          int m = mb + r;
          sbuf[m * 128 + (((n >> 3) ^ (m & 15)) * 8) + (n & 7)] =
              f2bf((acc[mi][ni][r] + bval) * sc);
        }
      }
    }
    __syncthreads();
    int row = tid >> 1, half = tid & 1;
    int m = m0 + row;
    int bb = m >> 11, s = m & 2047;
    for (int i = 0; i < 8; ++i) {
      int cg = half * 8 + i;
      int pg = cg ^ (row & 15);
      shortx8 v = *(const shortx8*)&sbuf[row * 128 + pg * 8];
      int ng = n0 + cg * 8;
      int h = ng >> 6, d = ng & 63;
      *(shortx8*)&dst[((size_t)(bb * 16 + h) * 2048 + s) * 64 + d] = v;
    }
  } else {
    for (int mi = 0; mi < 4; ++mi) {
      int mbase = m0 + wm * 64 + mi * 16 + lrow * 4;
      int bb = mbase >> 11, s = mbase & 2047;
      for (int ni = 0; ni < 4; ++ni) {
        int n = n0 + wn * 64 + ni * 16 + lcol;
        float bval = bias[n];
        int h = n >> 6, d = n & 63;
        uintx2 pk;
        pk.x = pkbf(acc[mi][ni][0] + bval, acc[mi][ni][1] + bval);
        pk.y = pkbf(acc[mi][ni][2] + bval, acc[mi][ni][3] + bval);
        *(uintx2*)&Vth[((size_t)(bb * 16 + h) * 64 + d) * 2048 + s] = pk;
      }
    }
  }
}

// ---------------- output projection: aout = ctx @ Wo^T + bo (fp32) ----------------
__global__ __launch_bounds__(256) void out_gemm(const u16* __restrict__ ctx,
                                                const u16* __restrict__ Wot,
                                                const float* __restrict__ bo,
                                                float* __restrict__ aout) {
  __shared__ u16 As[128 * 64];
  __shared__ u16 Bs[64 * 64];
  int m0 = blockIdx.x * 128;
  int n0 = blockIdx.y * 64;
  const int tid = threadIdx.x;
  const int wave = tid >> 6, lane = tid & 63;
  const int lrow = lane >> 4, lcol = lane & 15;
  const int wm = wave >> 1, wn = wave & 1;

  floatx4 acc[4][2];
  for (int mi = 0; mi < 4; ++mi)
    for (int ni = 0; ni < 2; ++ni)
      acc[mi][ni] = (floatx4){0.f, 0.f, 0.f, 0.f};

  const u16* ap[4];
  const u16* bp[2];
  for (int l = 0; l < 4; ++l) {
    int g = (l * 4 + wave) * 64 + lane;
    int r = g >> 3, c = g & 7;
    ap[l] = ctx + (size_t)(m0 + r) * 1024 + (c ^ (r & 7)) * 8;
  }
  for (int l = 0; l < 2; ++l) {
    int g = (l * 4 + wave) * 64 + lane;
    int r = g >> 3, c = g & 7;
    bp[l] = Wot + (size_t)(n0 + r) * 1024 + (c ^ (r & 7)) * 8;
  }

  for (int k0 = 0; k0 < 1024; k0 += 64) {
    __syncthreads();
    for (int l = 0; l < 4; ++l) { GLD16(ap[l], As + (l * 4 + wave) * 512); ap[l] += 64; }
    for (int l = 0; l < 2; ++l) { GLD16(bp[l], Bs + (l * 4 + wave) * 512); bp[l] += 64; }
    __syncthreads();
    for (int kk = 0; kk < 2; ++kk) {
      shortx8 af[4], bf[2];
      for (int mi = 0; mi < 4; ++mi) {
        int row = wm * 64 + mi * 16 + lcol;
        int gr = (kk * 4 + lrow) ^ (row & 7);
        af[mi] = *(const shortx8*)&As[row * 64 + gr * 8];
      }
      for (int ni = 0; ni < 2; ++ni) {
        int row = wn * 32 + ni * 16 + lcol;
        int gr = (kk * 4 + lrow) ^ (row & 7);
        bf[ni] = *(const shortx8*)&Bs[row * 64 + gr * 8];
      }
      for (int mi = 0; mi < 4; ++mi)
        for (int ni = 0; ni < 2; ++ni)
          acc[mi][ni] = __builtin_amdgcn_mfma_f32_16x16x32_bf16(af[mi], bf[ni], acc[mi][ni], 0, 0, 0);
    }
  }

  for (int mi = 0; mi < 4; ++mi) {
    int mbase = m0 + wm * 64 + mi * 16 + lrow * 4;
    for (int ni = 0; ni < 2; ++ni) {
      int n = n0 + wn * 32 + ni * 16 + lcol;
      float bval = bo[n];
      for (int r = 0; r < 4; ++r)
        aout[(size_t)(mbase + r) * 1024 + n] = acc[mi][ni][r] + bval;
    }
  }
}

// ---------------- flash attention ----------------
// grid (32_bh, 16_qt), 512 threads (8 waves x 16 q-rows). LDS 32KB: Q/P + K dbuf.
// V is NOT staged in LDS: its PV A-fragment (V^T[dt*16+lcol][kc+kk*32+lrow*8..+7])
// is 8 contiguous u16 per lane, 16B-aligned, 64B-coalesced per d-row, and
// L2-resident (XCD swizzle) -> plain global_load_dwordx4 at iter top, latency
// hidden under QK^T + exp2 + pack. Row-sums via ones-MFMA.
__global__ __launch_bounds__(512) void attn_kernel(const u16* __restrict__ Qh,
                                                   const u16* __restrict__ Kh,
                                                   const u16* __restrict__ Vth,
                                                   u16* __restrict__ ctx) {
  __shared__ u16 QPs[128 * 64];     // Q tile, then reused as P tile (wave-private rows)
  __shared__ u16 Ks[2][64 * 64];

  int bh = blockIdx.x;
  int b = bh >> 4, h = bh & 15;
  int q0 = blockIdx.y * 128;
  int tid = threadIdx.x;
  int wave = tid >> 6, lane = tid & 63;
  int lrow = lane >> 4, lcol = lane & 15;

  const u16* Qg = Qh + ((size_t)bh * 2048 + q0) * 64;
  for (int l = 0; l < 2; ++l) {
    int g = (l * 8 + wave) * 64 + lane;
    int r = g >> 3, c = g & 7;
    GLD16(Qg + r * 64 + ((c ^ (r & 7)) * 8), QPs + (l * 8 + wave) * 512);
  }

  const u16* Kbase = Kh + (size_t)bh * 2048 * 64;

  int g = wave * 64 + lane;
  int gr = g >> 3, gc = g & 7;
  int cc = (gc ^ (gr & 7)) * 8;
  const u16* kp = Kbase + (size_t)gr * 64 + cc;

  GLD16(kp, (u16*)Ks + wave * 512);
  kp += 4096;
  __syncthreads();

  // hoist Q fragments (B-operand: n = q = lane&15); wave owns q-rows wave*16..+15
  shortx8 qf[2];
  for (int kk = 0; kk < 2; ++kk) {
    int row = wave * 16 + lcol;
    int grr = (kk * 4 + lrow) ^ (row & 7);
    qf[kk] = *(const shortx8*)&QPs[row * 64 + grr * 8];
  }

  // V fragment pointers: one per dt, advanced 64 keys/iter
  const u16* vptr[4];
  {
    const u16* vb = Vth + (size_t)bh * 64 * 2048 + lrow * 8;
    for (int dt = 0; dt < 4; ++dt)
      vptr[dt] = vb + (size_t)(dt * 16 + lcol) * 2048;
  }

  const short one_bf = (short)0x3F80;
  const shortx8 ones8 = {one_bf, one_bf, one_bf, one_bf, one_bf, one_bf, one_bf, one_bf};

  floatx4 o[4];
  floatx4 lacc = (floatx4){0.f, 0.f, 0.f, 0.f};
  for (int dt = 0; dt < 4; ++dt) o[dt] = (floatx4){0.f, 0.f, 0.f, 0.f};

  for (int i = 0; i < 32; ++i) {
    int cur = i & 1;

    // V fragments for this chunk (plain loads; complete during QK/exp/pack)
    shortx8 vf[2][4];
    for (int kk = 0; kk < 2; ++kk)
      for (int dt = 0; dt < 4; ++dt)
        vf[kk][dt] = *(const shortx8*)(vptr[dt] + kk * 32);
    for (int dt = 0; dt < 4; ++dt) vptr[dt] += 64;

    if (i < 31) {
      GLD16(kp, (u16*)Ks + (cur ^ 1) * 4096 + wave * 512);
      kp += 4096;
    }

    // S^T[key][q] for this wave's 16 q-cols x 64 keys
    floatx4 sc[4];
    for (int kt = 0; kt < 4; ++kt)
      sc[kt] = (floatx4){0.f, 0.f, 0.f, 0.f};
    for (int kk = 0; kk < 2; ++kk) {
      for (int kt = 0; kt < 4; ++kt) {
        int row = kt * 16 + lcol;
        int grr = (kk * 4 + lrow) ^ (row & 7);
        shortx8 kf = *(const shortx8*)&Ks[cur][row * 64 + grr * 8];
        sc[kt] = __builtin_amdgcn_mfma_f32_16x16x32_bf16(kf, qf[kk], sc[kt], 0, 0, 0);
      }
    }

    // P = exp2(S^T) (Q pre-scaled); pack+write to LDS (b64 per kt)
    {
      int row = wave * 16 + lcol;
      for (int kt = 0; kt < 4; ++kt) {
        float p0 = __builtin_amdgcn_exp2f(sc[kt][0]);
        float p1 = __builtin_amdgcn_exp2f(sc[kt][1]);
        float p2 = __builtin_amdgcn_exp2f(sc[kt][2]);
        float p3 = __builtin_amdgcn_exp2f(sc[kt][3]);
        int gg = kt * 2 + (lrow >> 1);
        int addr = row * 64 + ((gg ^ (row & 7)) * 8) + (lrow & 1) * 4;
        uintx2 pk;
        pk.x = pkbf(p0, p1);
        pk.y = pkbf(p2, p3);
        *(uintx2*)&QPs[addr] = pk;
      }
    }

    // O^T += V^T P^T; row-sums l += ones * P^T (same pf operand)
    for (int kk = 0; kk < 2; ++kk) {
      int prow = wave * 16 + lcol;
      int pgr = (kk * 4 + lrow) ^ (prow & 7);
      shortx8 pf = *(const shortx8*)&QPs[prow * 64 + pgr * 8];
      lacc = __builtin_amdgcn_mfma_f32_16x16x32_bf16(ones8, pf, lacc, 0, 0, 0);
      for (int dt = 0; dt < 4; ++dt)
        o[dt] = __builtin_amdgcn_mfma_f32_16x16x32_bf16(vf[kk][dt], pf, o[dt], 0, 0, 0);
    }
    __syncthreads();
  }

  // epilogue: l = lacc[0] (all regs equal = column sum), O /= l, packed 8B stores
  {
    float inv = 1.0f / lacc[0];
    int s = q0 + wave * 16 + lcol;
    u16* dst = ctx + (size_t)(b * 2048 + s) * 1024 + h * 64 + lrow * 4;
    for (int dt = 0; dt < 4; ++dt) {
      uintx2 pk;
      pk.x = pkbf(o[dt][0] * inv, o[dt][1] * inv);
      pk.y = pkbf(o[dt][2] * inv, o[dt][3] * inv);
      *(uintx2*)(dst + dt * 16) = pk;
    }
  }
}

// ---------------- residual + LayerNorm ----------------
__global__ __launch_bounds__(256) void ln_kernel(const float* __restrict__ aout,
                                                 const float* __restrict__ x,
                                                 const float* __restrict__ gamma,
                                                 const float* __restrict__ beta,
                                                 float* __restrict__ out) {
  int row = blockIdx.x;
  int t = threadIdx.x;
  const float4* a4 = (const float4*)(aout + (size_t)row * 1024);
  const float4* x4 = (const float4*)(x + (size_t)row * 1024);
  float4 v = a4[t];
  float4 xv = x4[t];
  v.x += xv.x; v.y += xv.y; v.z += xv.z; v.w += xv.w;
  float s = v.x + v.y + v.z + v.w;
  float s2 = v.x * v.x + v.y * v.y + v.z * v.z + v.w * v.w;
  for (int off = 1; off < 64; off <<= 1) {
    s += __shfl_xor(s, off, 64);
    s2 += __shfl_xor(s2, off, 64);
  }
  __shared__ float red[8];
  int wave = t >> 6, lane = t & 63;
  if (lane == 0) { red[wave] = s; red[4 + wave] = s2; }
  __syncthreads();
  s = red[0] + red[1] + red[2] + red[3];
  s2 = red[4] + red[5] + red[6] + red[7];
  float mu = s * (1.0f / 1024.0f);
  float var = s2 * (1.0f / 1024.0f) - mu * mu;
  float rstd = rsqrtf(var + 1e-5f);
  float4 g = ((const float4*)gamma)[t];
  float4 be = ((const float4*)beta)[t];
  float4 y;
  y.x = (v.x - mu) * rstd * g.x + be.x;
  y.y = (v.y - mu) * rstd * g.y + be.y;
  y.z = (v.z - mu) * rstd * g.z + be.z;
  y.w = (v.w - mu) * rstd * g.w + be.w;
  ((float4*)(out + (size_t)row * 1024))[t] = y;
}

extern "C" void kernel_launch(void* const* d_in, const int* in_sizes, int n_in,
                              void* d_out, int out_size, void* d_ws, size_t ws_size,
                              hipStream_t stream) {
  const float* x     = (const float*)d_in[0];
  const float* Wq    = (const float*)d_in[1];
  const float* bq    = (const float*)d_in[2];
  const float* Wk    = (const float*)d_in[3];
  const float* bk    = (const float*)d_in[4];
  const float* Wv    = (const float*)d_in[5];
  const float* bv    = (const float*)d_in[6];
  const float* Wo    = (const float*)d_in[7];
  const float* bo    = (const float*)d_in[8];
  const float* gamma = (const float*)d_in[9];
  const float* beta  = (const float*)d_in[10];
  float* out = (float*)d_out;

  char* ws = (char*)d_ws;
  u16* xb   = (u16*)(ws);
  u16* Wt   = (u16*)(ws + ((size_t)8 << 20));
  u16* Qh   = (u16*)(ws + ((size_t)16 << 20));
  u16* Kh   = (u16*)(ws + ((size_t)24 << 20));
  u16* Vth  = (u16*)(ws + ((size_t)32 << 20));
  u16* ctx  = (u16*)(ws + ((size_t)40 << 20));
  float* aout = (float*)(ws + ((size_t)48 << 20));

  prep_kernel<<<8192, 256, 0, stream>>>(x, xb, Wq, Wk, Wv, Wo, Wt);
  qkv_gemm<<<dim3(32, 24), 256, 0, stream>>>(xb, Wt, bq, bk, bv, Qh, Kh, Vth);
  attn_kernel<<<dim3(32, 16), 512, 0, stream>>>(Qh, Kh, Vth, ctx);
  out_gemm<<<dim3(32, 16), 256, 0, stream>>>(ctx, Wt + (size_t)3 * 1024 * 1024, bo, aout);
  ln_kernel<<<4096, 256, 0, stream>>>(aout, x, gamma, beta, out);
}

// Round 8
// 208.534 us; speedup vs baseline: 1.3653x; 1.3653x over previous
//
#include <hip/hip_runtime.h>

typedef unsigned short u16;
typedef __attribute__((ext_vector_type(8))) short shortx8;
typedef __attribute__((ext_vector_type(4))) short shortx4;
typedef __attribute__((ext_vector_type(4))) float floatx4;
typedef __attribute__((ext_vector_type(2))) unsigned uintx2;

#define GLD16(gp, lp) __builtin_amdgcn_global_load_lds( \
    (__attribute__((address_space(1))) void*)(gp), \
    (__attribute__((address_space(3))) void*)(lp), 16, 0, 0)

__device__ __forceinline__ u16 f2bf(float f) {
  union { float f; unsigned u; } v; v.f = f;
  unsigned r = v.u + 0x7FFFu + ((v.u >> 16) & 1u);
  return (u16)(r >> 16);
}

// pack two f32 -> bf16x2 in one u32 (low = a, high = b)
__device__ __forceinline__ unsigned pkbf(float a, float b) {
#if __has_builtin(__builtin_amdgcn_cvt_pk_bf16_f32)
  auto r = __builtin_amdgcn_cvt_pk_bf16_f32(a, b);
  return __builtin_bit_cast(unsigned, r);
#else
  union { float f; unsigned u; } x, y; x.f = a; y.f = b;
  return __builtin_amdgcn_perm(y.u + 0x8000u, x.u + 0x8000u, 0x07060302u);
#endif
}

// bf16 16x16x16 MFMA (K=16): B-fragment k-layout (quad*4+j) matches the 16x16
// C-layout rows, so S^T accumulators feed PV directly from registers.
__device__ __forceinline__ floatx4 mfma16(uintx2 a, uintx2 b, floatx4 c) {
#if __has_builtin(__builtin_amdgcn_mfma_f32_16x16x16bf16_1k)
  return __builtin_amdgcn_mfma_f32_16x16x16bf16_1k(
      __builtin_bit_cast(shortx4, a), __builtin_bit_cast(shortx4, b), c, 0, 0, 0);
#elif __has_builtin(__builtin_amdgcn_mfma_f32_16x16x16_bf16)
  return __builtin_amdgcn_mfma_f32_16x16x16_bf16(
      __builtin_bit_cast(shortx4, a), __builtin_bit_cast(shortx4, b), c, 0, 0, 0);
#else
  floatx4 d = c;
  asm volatile("v_mfma_f32_16x16x16_bf16 %0, %1, %2, %0\n\ts_nop 7\n\ts_nop 7"
               : "+v"(d) : "v"(a), "v"(b));
  return d;
#endif
}

// ---------------- prep: cast x -> bf16  +  transpose-cast 4 weights ----------------
__global__ __launch_bounds__(256) void prep_kernel(const float* __restrict__ x,
                                                   u16* __restrict__ xb,
                                                   const float* __restrict__ Wq,
                                                   const float* __restrict__ Wk,
                                                   const float* __restrict__ Wv,
                                                   const float* __restrict__ Wo,
                                                   u16* __restrict__ Wt) {
  __shared__ u16 tile[32][33];
  int bid = blockIdx.x;
  int tid = threadIdx.x;
  if (bid < 4096) {
    int i = bid * 256 + tid;
    float4 v = ((const float4*)x)[i];
    uintx2 o;
    o.x = pkbf(v.x, v.y);
    o.y = pkbf(v.z, v.w);
    ((uintx2*)xb)[i] = o;
  } else {
    int block = bid - 4096;
    int mat = block >> 10;
    int rem = block & 1023;
    const float* W = (mat == 0) ? Wq : (mat == 1) ? Wk : (mat == 2) ? Wv : Wo;
    u16* dst = Wt + (size_t)mat * 1024 * 1024;
    int n0 = (rem & 31) * 32, k0 = (rem >> 5) * 32;
    int tx = tid & 31, ty = tid >> 5;
    for (int i = 0; i < 4; ++i)
      tile[ty + i * 8][tx] = f2bf(W[(size_t)(k0 + ty + i * 8) * 1024 + n0 + tx]);
    __syncthreads();
    for (int i = 0; i < 4; ++i)
      dst[(size_t)(n0 + ty + i * 8) * 1024 + k0 + tx] = tile[tx][ty + i * 8];
  }
}

// ---------------- shared GEMM core: C[128x128] += A[M,K] * Bt[N,K]^T ----------------
__device__ __forceinline__ void gemm_tile_core(const u16* __restrict__ A,
                                               const u16* __restrict__ Bt,
                                               int m0, int n0,
                                               u16* As, u16* Bs,
                                               floatx4 (&acc)[4][4]) {
  const int tid = threadIdx.x;
  const int wave = tid >> 6, lane = tid & 63;
  const int lrow = lane >> 4, lcol = lane & 15;
  const int wm = wave >> 1, wn = wave & 1;

  for (int mi = 0; mi < 4; ++mi)
    for (int ni = 0; ni < 4; ++ni)
      acc[mi][ni] = (floatx4){0.f, 0.f, 0.f, 0.f};

  const u16* ap[4];
  const u16* bp[4];
  for (int l = 0; l < 4; ++l) {
    int g = (l * 4 + wave) * 64 + lane;
    int r = g >> 3, c = g & 7;
    int cc = (c ^ (r & 7)) * 8;
    ap[l] = A + (size_t)(m0 + r) * 1024 + cc;
    bp[l] = Bt + (size_t)(n0 + r) * 1024 + cc;
  }

  for (int k0 = 0; k0 < 1024; k0 += 64) {
    __syncthreads();
    for (int l = 0; l < 4; ++l) {
      GLD16(ap[l], As + (l * 4 + wave) * 512);
      GLD16(bp[l], Bs + (l * 4 + wave) * 512);
      ap[l] += 64; bp[l] += 64;
    }
    __syncthreads();
    for (int kk = 0; kk < 2; ++kk) {
      shortx8 af[4], bf[4];
      for (int mi = 0; mi < 4; ++mi) {
        int row = wm * 64 + mi * 16 + lcol;
        int gr = (kk * 4 + lrow) ^ (row & 7);
        af[mi] = *(const shortx8*)&As[row * 64 + gr * 8];
      }
      for (int ni = 0; ni < 4; ++ni) {
        int row = wn * 64 + ni * 16 + lcol;
        int gr = (kk * 4 + lrow) ^ (row & 7);
        bf[ni] = *(const shortx8*)&Bs[row * 64 + gr * 8];
      }
      for (int mi = 0; mi < 4; ++mi)
        for (int ni = 0; ni < 4; ++ni)
          acc[mi][ni] = __builtin_amdgcn_mfma_f32_16x16x32_bf16(af[mi], bf[ni], acc[mi][ni], 0, 0, 0);
    }
  }
}

// ---------------- fused QKV projection ----------------
// Q is pre-scaled by log2(e)/sqrt(HD). Q/K epilogue transposes through the dead
// staging LDS to emit packed 16B stores instead of 64 scalar 2B stores.
__global__ __launch_bounds__(256) void qkv_gemm(const u16* __restrict__ xb,
                                                const u16* __restrict__ Wt,
                                                const float* __restrict__ bq,
                                                const float* __restrict__ bk,
                                                const float* __restrict__ bv,
                                                u16* __restrict__ Qh,
                                                u16* __restrict__ Kh,
                                                u16* __restrict__ Vth) {
  __shared__ u16 sbuf[128 * 128];   // As = first half, Bs = second half; reused as C-tile
  u16* As = sbuf;
  u16* Bs = sbuf + 128 * 64;
  int m0 = blockIdx.x * 128;
  int mat = blockIdx.y >> 3;
  int n0 = (blockIdx.y & 7) * 128;
  floatx4 acc[4][4];
  gemm_tile_core(xb, Wt + (size_t)mat * 1024 * 1024, m0, n0, As, Bs, acc);

  const float* bias = (mat == 0) ? bq : (mat == 1) ? bk : bv;
  const int tid = threadIdx.x;
  const int wave = tid >> 6, lane = tid & 63;
  const int lrow = lane >> 4, lcol = lane & 15;
  const int wm = wave >> 1, wn = wave & 1;
  const float qscale = 0.18033688011f;  // log2(e)/8

  if (mat < 2) {
    u16* dst = (mat == 0) ? Qh : Kh;
    float sc = (mat == 0) ? qscale : 1.0f;
    __syncthreads();  // staging LDS now dead; reuse as 128x128 C tile
    for (int mi = 0; mi < 4; ++mi) {
      int mb = wm * 64 + mi * 16 + lrow * 4;
      for (int ni = 0; ni < 4; ++ni) {
        int n = wn * 64 + ni * 16 + lcol;
        float bval = bias[n0 + n];
        for (int r = 0; r < 4; ++r) {
          int m = mb + r;
          sbuf[m * 128 + (((n >> 3) ^ (m & 15)) * 8) + (n & 7)] =
              f2bf((acc[mi][ni][r] + bval) * sc);
        }
      }
    }
    __syncthreads();
    int row = tid >> 1, half = tid & 1;
    int m = m0 + row;
    int bb = m >> 11, s = m & 2047;
    for (int i = 0; i < 8; ++i) {
      int cg = half * 8 + i;
      int pg = cg ^ (row & 15);
      shortx8 v = *(const shortx8*)&sbuf[row * 128 + pg * 8];
      int ng = n0 + cg * 8;
      int h = ng >> 6, d = ng & 63;
      *(shortx8*)&dst[((size_t)(bb * 16 + h) * 2048 + s) * 64 + d] = v;
    }
  } else {
    for (int mi = 0; mi < 4; ++mi) {
      int mbase = m0 + wm * 64 + mi * 16 + lrow * 4;
      int bb = mbase >> 11, s = mbase & 2047;
      for (int ni = 0; ni < 4; ++ni) {
        int n = n0 + wn * 64 + ni * 16 + lcol;
        float bval = bias[n];
        int h = n >> 6, d = n & 63;
        uintx2 pk;
        pk.x = pkbf(acc[mi][ni][0] + bval, acc[mi][ni][1] + bval);
        pk.y = pkbf(acc[mi][ni][2] + bval, acc[mi][ni][3] + bval);
        *(uintx2*)&Vth[((size_t)(bb * 16 + h) * 64 + d) * 2048 + s] = pk;
      }
    }
  }
}

// ---------------- output projection: aout = ctx @ Wo^T + bo (fp32) ----------------
__global__ __launch_bounds__(256) void out_gemm(const u16* __restrict__ ctx,
                                                const u16* __restrict__ Wot,
                                                const float* __restrict__ bo,
                                                float* __restrict__ aout) {
  __shared__ u16 As[128 * 64];
  __shared__ u16 Bs[64 * 64];
  int m0 = blockIdx.x * 128;
  int n0 = blockIdx.y * 64;
  const int tid = threadIdx.x;
  const int wave = tid >> 6, lane = tid & 63;
  const int lrow = lane >> 4, lcol = lane & 15;
  const int wm = wave >> 1, wn = wave & 1;

  floatx4 acc[4][2];
  for (int mi = 0; mi < 4; ++mi)
    for (int ni = 0; ni < 2; ++ni)
      acc[mi][ni] = (floatx4){0.f, 0.f, 0.f, 0.f};

  const u16* ap[4];
  const u16* bp[2];
  for (int l = 0; l < 4; ++l) {
    int g = (l * 4 + wave) * 64 + lane;
    int r = g >> 3, c = g & 7;
    ap[l] = ctx + (size_t)(m0 + r) * 1024 + (c ^ (r & 7)) * 8;
  }
  for (int l = 0; l < 2; ++l) {
    int g = (l * 4 + wave) * 64 + lane;
    int r = g >> 3, c = g & 7;
    bp[l] = Wot + (size_t)(n0 + r) * 1024 + (c ^ (r & 7)) * 8;
  }

  for (int k0 = 0; k0 < 1024; k0 += 64) {
    __syncthreads();
    for (int l = 0; l < 4; ++l) { GLD16(ap[l], As + (l * 4 + wave) * 512); ap[l] += 64; }
    for (int l = 0; l < 2; ++l) { GLD16(bp[l], Bs + (l * 4 + wave) * 512); bp[l] += 64; }
    __syncthreads();
    for (int kk = 0; kk < 2; ++kk) {
      shortx8 af[4], bf[2];
      for (int mi = 0; mi < 4; ++mi) {
        int row = wm * 64 + mi * 16 + lcol;
        int gr = (kk * 4 + lrow) ^ (row & 7);
        af[mi] = *(const shortx8*)&As[row * 64 + gr * 8];
      }
      for (int ni = 0; ni < 2; ++ni) {
        int row = wn * 32 + ni * 16 + lcol;
        int gr = (kk * 4 + lrow) ^ (row & 7);
        bf[ni] = *(const shortx8*)&Bs[row * 64 + gr * 8];
      }
      for (int mi = 0; mi < 4; ++mi)
        for (int ni = 0; ni < 2; ++ni)
          acc[mi][ni] = __builtin_amdgcn_mfma_f32_16x16x32_bf16(af[mi], bf[ni], acc[mi][ni], 0, 0, 0);
    }
  }

  for (int mi = 0; mi < 4; ++mi) {
    int mbase = m0 + wm * 64 + mi * 16 + lrow * 4;
    for (int ni = 0; ni < 2; ++ni) {
      int n = n0 + wn * 32 + ni * 16 + lcol;
      float bval = bo[n];
      for (int r = 0; r < 4; ++r)
        aout[(size_t)(mbase + r) * 1024 + n] = acc[mi][ni][r] + bval;
    }
  }
}

// ---------------- flash attention ----------------
// grid (32_bh, 16_qt), 512 threads (8 waves x 16 q-rows). K and V staged in LDS
// (dbuf, GLD16 — load-once-share-eight; R7 showed un-staged V = 8x L2 traffic).
// P never touches LDS: S^T C-layout rows (key = quad*4+r) are exactly the
// B-fragment k-layout of 16x16x16 MFMA, so PV consumes packed sc registers
// directly (4 K=16 MFMAs per kt). Row sums via ones-MFMA; l = lacc[0].
__global__ __launch_bounds__(512) void attn_kernel(const u16* __restrict__ Qh,
                                                   const u16* __restrict__ Kh,
                                                   const u16* __restrict__ Vth,
                                                   u16* __restrict__ ctx) {
  __shared__ u16 QPs[128 * 64];     // Q tile (dead after fragment hoist)
  __shared__ u16 Ks[2][64 * 64];
  __shared__ u16 Vs[2][64 * 64];

  int bh = blockIdx.x;
  int b = bh >> 4, h = bh & 15;
  int q0 = blockIdx.y * 128;
  int tid = threadIdx.x;
  int wave = tid >> 6, lane = tid & 63;
  int lrow = lane >> 4, lcol = lane & 15;

  const u16* Qg = Qh + ((size_t)bh * 2048 + q0) * 64;
  for (int l = 0; l < 2; ++l) {
    int g = (l * 8 + wave) * 64 + lane;
    int r = g >> 3, c = g & 7;
    GLD16(Qg + r * 64 + ((c ^ (r & 7)) * 8), QPs + (l * 8 + wave) * 512);
  }

  const u16* Kbase = Kh + (size_t)bh * 2048 * 64;
  const u16* Vbase = Vth + (size_t)bh * 64 * 2048;

  int g = wave * 64 + lane;
  int gr = g >> 3, gc = g & 7;
  int cc = (gc ^ (gr & 7)) * 8;
  const u16* kp = Kbase + (size_t)gr * 64 + cc;
  const u16* vp = Vbase + (size_t)gr * 2048 + cc;

  GLD16(kp, (u16*)Ks + wave * 512);
  GLD16(vp, (u16*)Vs + wave * 512);
  kp += 4096;
  vp += 64;
  __syncthreads();

  // hoist Q fragments (B-operand: n = q = lane&15); wave owns q-rows wave*16..+15
  shortx8 qf[2];
  for (int kk = 0; kk < 2; ++kk) {
    int row = wave * 16 + lcol;
    int grr = (kk * 4 + lrow) ^ (row & 7);
    qf[kk] = *(const shortx8*)&QPs[row * 64 + grr * 8];
  }

  const uintx2 ones2 = {0x3F803F80u, 0x3F803F80u};  // 4 x bf16(1.0)

  floatx4 o[4];
  floatx4 lacc = (floatx4){0.f, 0.f, 0.f, 0.f};
  for (int dt = 0; dt < 4; ++dt) o[dt] = (floatx4){0.f, 0.f, 0.f, 0.f};

  for (int i = 0; i < 32; ++i) {
    int cur = i & 1;
    if (i < 31) {
      GLD16(kp, (u16*)Ks + (cur ^ 1) * 4096 + wave * 512);
      GLD16(vp, (u16*)Vs + (cur ^ 1) * 4096 + wave * 512);
      kp += 4096;
      vp += 64;
    }

    // S^T[key][q] for this wave's 16 q-cols x 64 keys
    floatx4 sc[4];
    for (int kt = 0; kt < 4; ++kt)
      sc[kt] = (floatx4){0.f, 0.f, 0.f, 0.f};
    for (int kk = 0; kk < 2; ++kk) {
      for (int kt = 0; kt < 4; ++kt) {
        int row = kt * 16 + lcol;
        int grr = (kk * 4 + lrow) ^ (row & 7);
        shortx8 kf = *(const shortx8*)&Ks[cur][row * 64 + grr * 8];
        sc[kt] = __builtin_amdgcn_mfma_f32_16x16x32_bf16(kf, qf[kk], sc[kt], 0, 0, 0);
      }
    }

    // P = exp2(S^T); pack -> B-fragments; PV + row sums, all register-direct
    int vsub = (lrow & 1) * 4;
    for (int kt = 0; kt < 4; ++kt) {
      uintx2 pf;
      pf.x = pkbf(__builtin_amdgcn_exp2f(sc[kt][0]), __builtin_amdgcn_exp2f(sc[kt][1]));
      pf.y = pkbf(__builtin_amdgcn_exp2f(sc[kt][2]), __builtin_amdgcn_exp2f(sc[kt][3]));
      lacc = mfma16(ones2, pf, lacc);
      int g0 = kt * 2 + (lrow >> 1);
      for (int dt = 0; dt < 4; ++dt) {
        int row = dt * 16 + lcol;
        uintx2 vf = *(const uintx2*)&Vs[cur][row * 64 + ((g0 ^ (row & 7)) * 8) + vsub];
        o[dt] = mfma16(vf, pf, o[dt]);
      }
    }
    __syncthreads();
  }

  // epilogue: l = lacc[0] (all regs equal = column sum), O /= l, packed 8B stores
  {
    float inv = 1.0f / lacc[0];
    int s = q0 + wave * 16 + lcol;
    u16* dst = ctx + (size_t)(b * 2048 + s) * 1024 + h * 64 + lrow * 4;
    for (int dt = 0; dt < 4; ++dt) {
      uintx2 pk;
      pk.x = pkbf(o[dt][0] * inv, o[dt][1] * inv);
      pk.y = pkbf(o[dt][2] * inv, o[dt][3] * inv);
      *(uintx2*)(dst + dt * 16) = pk;
    }
  }
}

// ---------------- residual + LayerNorm ----------------
__global__ __launch_bounds__(256) void ln_kernel(const float* __restrict__ aout,
                                                 const float* __restrict__ x,
                                                 const float* __restrict__ gamma,
                                                 const float* __restrict__ beta,
                                                 float* __restrict__ out) {
  int row = blockIdx.x;
  int t = threadIdx.x;
  const float4* a4 = (const float4*)(aout + (size_t)row * 1024);
  const float4* x4 = (const float4*)(x + (size_t)row * 1024);
  float4 v = a4[t];
  float4 xv = x4[t];
  v.x += xv.x; v.y += xv.y; v.z += xv.z; v.w += xv.w;
  float s = v.x + v.y + v.z + v.w;
  float s2 = v.x * v.x + v.y * v.y + v.z * v.z + v.w * v.w;
  for (int off = 1; off < 64; off <<= 1) {
    s += __shfl_xor(s, off, 64);
    s2 += __shfl_xor(s2, off, 64);
  }
  __shared__ float red[8];
  int wave = t >> 6, lane = t & 63;
  if (lane == 0) { red[wave] = s; red[4 + wave] = s2; }
  __syncthreads();
  s = red[0] + red[1] + red[2] + red[3];
  s2 = red[4] + red[5] + red[6] + red[7];
  float mu = s * (1.0f / 1024.0f);
  float var = s2 * (1.0f / 1024.0f) - mu * mu;
  float rstd = rsqrtf(var + 1e-5f);
  float4 g = ((const float4*)gamma)[t];
  float4 be = ((const float4*)beta)[t];
  float4 y;
  y.x = (v.x - mu) * rstd * g.x + be.x;
  y.y = (v.y - mu) * rstd * g.y + be.y;
  y.z = (v.z - mu) * rstd * g.z + be.z;
  y.w = (v.w - mu) * rstd * g.w + be.w;
  ((float4*)(out + (size_t)row * 1024))[t] = y;
}

extern "C" void kernel_launch(void* const* d_in, const int* in_sizes, int n_in,
                              void* d_out, int out_size, void* d_ws, size_t ws_size,
                              hipStream_t stream) {
  const float* x     = (const float*)d_in[0];
  const float* Wq    = (const float*)d_in[1];
  const float* bq    = (const float*)d_in[2];
  const float* Wk    = (const float*)d_in[3];
  const float* bk    = (const float*)d_in[4];
  const float* Wv    = (const float*)d_in[5];
  const float* bv    = (const float*)d_in[6];
  const float* Wo    = (const float*)d_in[7];
  const float* bo    = (const float*)d_in[8];
  const float* gamma = (const float*)d_in[9];
  const float* beta  = (const float*)d_in[10];
  float* out = (float*)d_out;

  char* ws = (char*)d_ws;
  u16* xb   = (u16*)(ws);
  u16* Wt   = (u16*)(ws + ((size_t)8 << 20));
  u16* Qh   = (u16*)(ws + ((size_t)16 << 20));
  u16* Kh   = (u16*)(ws + ((size_t)24 << 20));
  u16* Vth  = (u16*)(ws + ((size_t)32 << 20));
  u16* ctx  = (u16*)(ws + ((size_t)40 << 20));
  float* aout = (float*)(ws + ((size_t)48 << 20));

  prep_kernel<<<8192, 256, 0, stream>>>(x, xb, Wq, Wk, Wv, Wo, Wt);
  qkv_gemm<<<dim3(32, 24), 256, 0, stream>>>(xb, Wt, bq, bk, bv, Qh, Kh, Vth);
  attn_kernel<<<dim3(32, 16), 512, 0, stream>>>(Qh, Kh, Vth, ctx);
  out_gemm<<<dim3(32, 16), 256, 0, stream>>>(ctx, Wt + (size_t)3 * 1024 * 1024, bo, aout);
  ln_kernel<<<4096, 256, 0, stream>>>(aout, x, gamma, beta, out);
}

// Round 9
// 207.353 us; speedup vs baseline: 1.3731x; 1.0057x over previous
//
#include <hip/hip_runtime.h>

typedef unsigned short u16;
typedef __attribute__((ext_vector_type(8))) short shortx8;
typedef __attribute__((ext_vector_type(4))) float floatx4;
typedef __attribute__((ext_vector_type(2))) unsigned uintx2;

#define GLD16(gp, lp) __builtin_amdgcn_global_load_lds( \
    (__attribute__((address_space(1))) void*)(gp), \
    (__attribute__((address_space(3))) void*)(lp), 16, 0, 0)

__device__ __forceinline__ u16 f2bf(float f) {
  union { float f; unsigned u; } v; v.f = f;
  unsigned r = v.u + 0x7FFFu + ((v.u >> 16) & 1u);
  return (u16)(r >> 16);
}

// pack two f32 -> bf16x2 in one u32 (low = a, high = b)
__device__ __forceinline__ unsigned pkbf(float a, float b) {
#if __has_builtin(__builtin_amdgcn_cvt_pk_bf16_f32)
  auto r = __builtin_amdgcn_cvt_pk_bf16_f32(a, b);
  return __builtin_bit_cast(unsigned, r);
#else
  union { float f; unsigned u; } x, y; x.f = a; y.f = b;
  return __builtin_amdgcn_perm(y.u + 0x8000u, x.u + 0x8000u, 0x07060302u);
#endif
}

// ---------------- prep: cast x -> bf16  +  transpose-cast 4 weights ----------------
__global__ __launch_bounds__(256) void prep_kernel(const float* __restrict__ x,
                                                   u16* __restrict__ xb,
                                                   const float* __restrict__ Wq,
                                                   const float* __restrict__ Wk,
                                                   const float* __restrict__ Wv,
                                                   const float* __restrict__ Wo,
                                                   u16* __restrict__ Wt) {
  __shared__ u16 tile[32][33];
  int bid = blockIdx.x;
  int tid = threadIdx.x;
  if (bid < 4096) {
    int i = bid * 256 + tid;
    float4 v = ((const float4*)x)[i];
    uintx2 o;
    o.x = pkbf(v.x, v.y);
    o.y = pkbf(v.z, v.w);
    ((uintx2*)xb)[i] = o;
  } else {
    int block = bid - 4096;
    int mat = block >> 10;
    int rem = block & 1023;
    const float* W = (mat == 0) ? Wq : (mat == 1) ? Wk : (mat == 2) ? Wv : Wo;
    u16* dst = Wt + (size_t)mat * 1024 * 1024;
    int n0 = (rem & 31) * 32, k0 = (rem >> 5) * 32;
    int tx = tid & 31, ty = tid >> 5;
    for (int i = 0; i < 4; ++i)
      tile[ty + i * 8][tx] = f2bf(W[(size_t)(k0 + ty + i * 8) * 1024 + n0 + tx]);
    __syncthreads();
    for (int i = 0; i < 4; ++i)
      dst[(size_t)(n0 + ty + i * 8) * 1024 + k0 + tx] = tile[tx][ty + i * 8];
  }
}

// ---------------- shared GEMM core: C[128x128] += A[M,K] * Bt[N,K]^T ----------------
__device__ __forceinline__ void gemm_tile_core(const u16* __restrict__ A,
                                               const u16* __restrict__ Bt,
                                               int m0, int n0,
                                               u16* As, u16* Bs,
                                               floatx4 (&acc)[4][4]) {
  const int tid = threadIdx.x;
  const int wave = tid >> 6, lane = tid & 63;
  const int lrow = lane >> 4, lcol = lane & 15;
  const int wm = wave >> 1, wn = wave & 1;

  for (int mi = 0; mi < 4; ++mi)
    for (int ni = 0; ni < 4; ++ni)
      acc[mi][ni] = (floatx4){0.f, 0.f, 0.f, 0.f};

  const u16* ap[4];
  const u16* bp[4];
  for (int l = 0; l < 4; ++l) {
    int g = (l * 4 + wave) * 64 + lane;
    int r = g >> 3, c = g & 7;
    int cc = (c ^ (r & 7)) * 8;
    ap[l] = A + (size_t)(m0 + r) * 1024 + cc;
    bp[l] = Bt + (size_t)(n0 + r) * 1024 + cc;
  }

  for (int k0 = 0; k0 < 1024; k0 += 64) {
    __syncthreads();
    for (int l = 0; l < 4; ++l) {
      GLD16(ap[l], As + (l * 4 + wave) * 512);
      GLD16(bp[l], Bs + (l * 4 + wave) * 512);
      ap[l] += 64; bp[l] += 64;
    }
    __syncthreads();
    for (int kk = 0; kk < 2; ++kk) {
      shortx8 af[4], bf[4];
      for (int mi = 0; mi < 4; ++mi) {
        int row = wm * 64 + mi * 16 + lcol;
        int gr = (kk * 4 + lrow) ^ (row & 7);
        af[mi] = *(const shortx8*)&As[row * 64 + gr * 8];
      }
      for (int ni = 0; ni < 4; ++ni) {
        int row = wn * 64 + ni * 16 + lcol;
        int gr = (kk * 4 + lrow) ^ (row & 7);
        bf[ni] = *(const shortx8*)&Bs[row * 64 + gr * 8];
      }
      for (int mi = 0; mi < 4; ++mi)
        for (int ni = 0; ni < 4; ++ni)
          acc[mi][ni] = __builtin_amdgcn_mfma_f32_16x16x32_bf16(af[mi], bf[ni], acc[mi][ni], 0, 0, 0);
    }
  }
}

// ---------------- fused QKV projection ----------------
// Q is pre-scaled by log2(e)/sqrt(HD). Q/K epilogue transposes through the dead
// staging LDS to emit packed 16B stores instead of 64 scalar 2B stores.
__global__ __launch_bounds__(256) void qkv_gemm(const u16* __restrict__ xb,
                                                const u16* __restrict__ Wt,
                                                const float* __restrict__ bq,
                                                const float* __restrict__ bk,
                                                const float* __restrict__ bv,
                                                u16* __restrict__ Qh,
                                                u16* __restrict__ Kh,
                                                u16* __restrict__ Vth) {
  __shared__ u16 sbuf[128 * 128];   // As = first half, Bs = second half; reused as C-tile
  u16* As = sbuf;
  u16* Bs = sbuf + 128 * 64;
  int m0 = blockIdx.x * 128;
  int mat = blockIdx.y >> 3;
  int n0 = (blockIdx.y & 7) * 128;
  floatx4 acc[4][4];
  gemm_tile_core(xb, Wt + (size_t)mat * 1024 * 1024, m0, n0, As, Bs, acc);

  const float* bias = (mat == 0) ? bq : (mat == 1) ? bk : bv;
  const int tid = threadIdx.x;
  const int wave = tid >> 6, lane = tid & 63;
  const int lrow = lane >> 4, lcol = lane & 15;
  const int wm = wave >> 1, wn = wave & 1;
  const float qscale = 0.18033688011f;  // log2(e)/8

  if (mat < 2) {
    u16* dst = (mat == 0) ? Qh : Kh;
    float sc = (mat == 0) ? qscale : 1.0f;
    __syncthreads();  // staging LDS now dead; reuse as 128x128 C tile
    for (int mi = 0; mi < 4; ++mi) {
      int mb = wm * 64 + mi * 16 + lrow * 4;
      for (int ni = 0; ni < 4; ++ni) {
        int n = wn * 64 + ni * 16 + lcol;
        float bval = bias[n0 + n];
        for (int r = 0; r < 4; ++r) {
          int m = mb + r;
          sbuf[m * 128 + (((n >> 3) ^ (m & 15)) * 8) + (n & 7)] =
              f2bf((acc[mi][ni][r] + bval) * sc);
        }
      }
    }
    __syncthreads();
    int row = tid >> 1, half = tid & 1;
    int m = m0 + row;
    int bb = m >> 11, s = m & 2047;
    for (int i = 0; i < 8; ++i) {
      int cg = half * 8 + i;
      int pg = cg ^ (row & 15);
      shortx8 v = *(const shortx8*)&sbuf[row * 128 + pg * 8];
      int ng = n0 + cg * 8;
      int h = ng >> 6, d = ng & 63;
      *(shortx8*)&dst[((size_t)(bb * 16 + h) * 2048 + s) * 64 + d] = v;
    }
  } else {
    for (int mi = 0; mi < 4; ++mi) {
      int mbase = m0 + wm * 64 + mi * 16 + lrow * 4;
      int bb = mbase >> 11, s = mbase & 2047;
      for (int ni = 0; ni < 4; ++ni) {
        int n = n0 + wn * 64 + ni * 16 + lcol;
        float bval = bias[n];
        int h = n >> 6, d = n & 63;
        uintx2 pk;
        pk.x = pkbf(acc[mi][ni][0] + bval, acc[mi][ni][1] + bval);
        pk.y = pkbf(acc[mi][ni][2] + bval, acc[mi][ni][3] + bval);
        *(uintx2*)&Vth[((size_t)(bb * 16 + h) * 64 + d) * 2048 + s] = pk;
      }
    }
  }
}

// ---------------- output projection: aout = ctx @ Wo^T + bo (fp32) ----------------
__global__ __launch_bounds__(256) void out_gemm(const u16* __restrict__ ctx,
                                                const u16* __restrict__ Wot,
                                                const float* __restrict__ bo,
                                                float* __restrict__ aout) {
  __shared__ u16 As[128 * 64];
  __shared__ u16 Bs[64 * 64];
  int m0 = blockIdx.x * 128;
  int n0 = blockIdx.y * 64;
  const int tid = threadIdx.x;
  const int wave = tid >> 6, lane = tid & 63;
  const int lrow = lane >> 4, lcol = lane & 15;
  const int wm = wave >> 1, wn = wave & 1;

  floatx4 acc[4][2];
  for (int mi = 0; mi < 4; ++mi)
    for (int ni = 0; ni < 2; ++ni)
      acc[mi][ni] = (floatx4){0.f, 0.f, 0.f, 0.f};

  const u16* ap[4];
  const u16* bp[2];
  for (int l = 0; l < 4; ++l) {
    int g = (l * 4 + wave) * 64 + lane;
    int r = g >> 3, c = g & 7;
    ap[l] = ctx + (size_t)(m0 + r) * 1024 + (c ^ (r & 7)) * 8;
  }
  for (int l = 0; l < 2; ++l) {
    int g = (l * 4 + wave) * 64 + lane;
    int r = g >> 3, c = g & 7;
    bp[l] = Wot + (size_t)(n0 + r) * 1024 + (c ^ (r & 7)) * 8;
  }

  for (int k0 = 0; k0 < 1024; k0 += 64) {
    __syncthreads();
    for (int l = 0; l < 4; ++l) { GLD16(ap[l], As + (l * 4 + wave) * 512); ap[l] += 64; }
    for (int l = 0; l < 2; ++l) { GLD16(bp[l], Bs + (l * 4 + wave) * 512); bp[l] += 64; }
    __syncthreads();
    for (int kk = 0; kk < 2; ++kk) {
      shortx8 af[4], bf[2];
      for (int mi = 0; mi < 4; ++mi) {
        int row = wm * 64 + mi * 16 + lcol;
        int gr = (kk * 4 + lrow) ^ (row & 7);
        af[mi] = *(const shortx8*)&As[row * 64 + gr * 8];
      }
      for (int ni = 0; ni < 2; ++ni) {
        int row = wn * 32 + ni * 16 + lcol;
        int gr = (kk * 4 + lrow) ^ (row & 7);
        bf[ni] = *(const shortx8*)&Bs[row * 64 + gr * 8];
      }
      for (int mi = 0; mi < 4; ++mi)
        for (int ni = 0; ni < 2; ++ni)
          acc[mi][ni] = __builtin_amdgcn_mfma_f32_16x16x32_bf16(af[mi], bf[ni], acc[mi][ni], 0, 0, 0);
    }
  }

  for (int mi = 0; mi < 4; ++mi) {
    int mbase = m0 + wm * 64 + mi * 16 + lrow * 4;
    for (int ni = 0; ni < 2; ++ni) {
      int n = n0 + wn * 32 + ni * 16 + lcol;
      float bval = bo[n];
      for (int r = 0; r < 4; ++r)
        aout[(size_t)(mbase + r) * 1024 + n] = acc[mi][ni][r] + bval;
    }
  }
}

// ---------------- flash attention ----------------
// grid (32_bh, 16_qt), 512 threads (8 waves x 16 q-rows). BK=128: two 64-key
// sub-phases per barrier period -> 16 barriers instead of 32 at unchanged
// occupancy (LDS 80KB = 2 blocks/CU, same as before; grid-capped anyway).
// R6 inner loop per sub-phase: QK (K=32 MFMA) -> exp2/pack -> P via LDS (b64
// writes, b128 reads) -> PV (K=32 MFMA) + ones-MFMA row sums.
__global__ __launch_bounds__(512) void attn_kernel(const u16* __restrict__ Qh,
                                                   const u16* __restrict__ Kh,
                                                   const u16* __restrict__ Vth,
                                                   u16* __restrict__ ctx) {
  __shared__ u16 QPs[128 * 64];       // Q tile, then P tile (wave-private rows)
  __shared__ u16 Ks[2][128 * 64];     // K chunk: [key 128][d 64], 8 granules/row
  __shared__ u16 Vs[2][64 * 128];     // V^T chunk: [d 64][key 128], 16 granules/row

  int bh = blockIdx.x;
  int b = bh >> 4, h = bh & 15;
  int q0 = blockIdx.y * 128;
  int tid = threadIdx.x;
  int wave = tid >> 6, lane = tid & 63;
  int lrow = lane >> 4, lcol = lane & 15;

  const u16* Qg = Qh + ((size_t)bh * 2048 + q0) * 64;
  for (int l = 0; l < 2; ++l) {
    int g = (l * 8 + wave) * 64 + lane;
    int r = g >> 3, c = g & 7;
    GLD16(Qg + r * 64 + ((c ^ (r & 7)) * 8), QPs + (l * 8 + wave) * 512);
  }

  const u16* Kbase = Kh + (size_t)bh * 2048 * 64;
  const u16* Vbase = Vth + (size_t)bh * 64 * 2048;

  // staging pointers: per wave 2 GLD16 for K (128x64) and 2 for V (64x128)
  const u16* kp[2];
  const u16* vp[2];
  u16* kdst[2];
  u16* vdst[2];
  for (int l = 0; l < 2; ++l) {
    int gid = (l * 8 + wave) * 64 + lane;
    int kr = gid >> 3, kc8 = gid & 7;
    kp[l] = Kbase + (size_t)kr * 64 + ((kc8 ^ (kr & 7)) * 8);
    kdst[l] = (u16*)Ks + gid * 8;
    int vr = gid >> 4, vc = gid & 15;
    vp[l] = Vbase + (size_t)vr * 2048 + ((vc ^ (vr & 7)) * 8);
    vdst[l] = (u16*)Vs + gid * 8;
  }

  // prefetch chunk 0 into buffer 0
  for (int l = 0; l < 2; ++l) {
    GLD16(kp[l], kdst[l]);
    GLD16(vp[l], vdst[l]);
    kp[l] += 8192;   // +128 key rows * 64
    vp[l] += 128;    // +128 key cols
  }
  __syncthreads();

  // hoist Q fragments (B-operand: n = q = lane&15); wave owns q-rows wave*16..+15
  shortx8 qf[2];
  for (int kk = 0; kk < 2; ++kk) {
    int row = wave * 16 + lcol;
    int grr = (kk * 4 + lrow) ^ (row & 7);
    qf[kk] = *(const shortx8*)&QPs[row * 64 + grr * 8];
  }

  const short one_bf = (short)0x3F80;
  const shortx8 ones8 = {one_bf, one_bf, one_bf, one_bf, one_bf, one_bf, one_bf, one_bf};

  floatx4 o[4];
  floatx4 lacc = (floatx4){0.f, 0.f, 0.f, 0.f};
  for (int dt = 0; dt < 4; ++dt) o[dt] = (floatx4){0.f, 0.f, 0.f, 0.f};

  int prow = wave * 16 + lcol;
  int p7 = prow & 7;

  for (int i = 0; i < 16; ++i) {
    int cur = i & 1;
    if (i < 15) {
      for (int l = 0; l < 2; ++l) {
        GLD16(kp[l], kdst[l] + (cur ^ 1) * 8192);
        GLD16(vp[l], vdst[l] + (cur ^ 1) * 8192);
        kp[l] += 8192;
        vp[l] += 128;
      }
    }
    const u16* Kc = Ks[cur];
    const u16* Vc = Vs[cur];

    for (int p = 0; p < 2; ++p) {
      // S^T[key][q]: 64 keys (sub-phase p) x 16 q-cols
      floatx4 sc[4];
      for (int kt = 0; kt < 4; ++kt)
        sc[kt] = (floatx4){0.f, 0.f, 0.f, 0.f};
      for (int kk = 0; kk < 2; ++kk) {
        for (int kt = 0; kt < 4; ++kt) {
          int r = p * 64 + kt * 16 + lcol;
          int grr = (kk * 4 + lrow) ^ (r & 7);
          shortx8 kf = *(const shortx8*)&Kc[r * 64 + grr * 8];
          sc[kt] = __builtin_amdgcn_mfma_f32_16x16x32_bf16(kf, qf[kk], sc[kt], 0, 0, 0);
        }
      }

      // P = exp2(S^T) (Q pre-scaled); pack+write to LDS (b64 per kt)
      for (int kt = 0; kt < 4; ++kt) {
        uintx2 pk;
        pk.x = pkbf(__builtin_amdgcn_exp2f(sc[kt][0]), __builtin_amdgcn_exp2f(sc[kt][1]));
        pk.y = pkbf(__builtin_amdgcn_exp2f(sc[kt][2]), __builtin_amdgcn_exp2f(sc[kt][3]));
        int gg = kt * 2 + (lrow >> 1);
        int addr = prow * 64 + ((gg ^ p7) * 8) + (lrow & 1) * 4;
        *(uintx2*)&QPs[addr] = pk;
      }

      // O^T += V^T P^T; row-sums l += ones * P^T (same pf operand)
      for (int kk = 0; kk < 2; ++kk) {
        int pgr = (kk * 4 + lrow) ^ p7;
        shortx8 pf = *(const shortx8*)&QPs[prow * 64 + pgr * 8];
        lacc = __builtin_amdgcn_mfma_f32_16x16x32_bf16(ones8, pf, lacc, 0, 0, 0);
        for (int dt = 0; dt < 4; ++dt) {
          int r = dt * 16 + lcol;
          int g = p * 8 + kk * 4 + lrow;
          shortx8 vf = *(const shortx8*)&Vc[r * 128 + ((g ^ (r & 7)) * 8)];
          o[dt] = __builtin_amdgcn_mfma_f32_16x16x32_bf16(vf, pf, o[dt], 0, 0, 0);
        }
      }
    }
    __syncthreads();
  }

  // epilogue: l = lacc[0] (all regs equal = column sum), O /= l, packed 8B stores
  {
    float inv = 1.0f / lacc[0];
    int s = q0 + wave * 16 + lcol;
    u16* dst = ctx + (size_t)(b * 2048 + s) * 1024 + h * 64 + lrow * 4;
    for (int dt = 0; dt < 4; ++dt) {
      uintx2 pk;
      pk.x = pkbf(o[dt][0] * inv, o[dt][1] * inv);
      pk.y = pkbf(o[dt][2] * inv, o[dt][3] * inv);
      *(uintx2*)(dst + dt * 16) = pk;
    }
  }
}

// ---------------- residual + LayerNorm ----------------
__global__ __launch_bounds__(256) void ln_kernel(const float* __restrict__ aout,
                                                 const float* __restrict__ x,
                                                 const float* __restrict__ gamma,
                                                 const float* __restrict__ beta,
                                                 float* __restrict__ out) {
  int row = blockIdx.x;
  int t = threadIdx.x;
  const float4* a4 = (const float4*)(aout + (size_t)row * 1024);
  const float4* x4 = (const float4*)(x + (size_t)row * 1024);
  float4 v = a4[t];
  float4 xv = x4[t];
  v.x += xv.x; v.y += xv.y; v.z += xv.z; v.w += xv.w;
  float s = v.x + v.y + v.z + v.w;
  float s2 = v.x * v.x + v.y * v.y + v.z * v.z + v.w * v.w;
  for (int off = 1; off < 64; off <<= 1) {
    s += __shfl_xor(s, off, 64);
    s2 += __shfl_xor(s2, off, 64);
  }
  __shared__ float red[8];
  int wave = t >> 6, lane = t & 63;
  if (lane == 0) { red[wave] = s; red[4 + wave] = s2; }
  __syncthreads();
  s = red[0] + red[1] + red[2] + red[3];
  s2 = red[4] + red[5] + red[6] + red[7];
  float mu = s * (1.0f / 1024.0f);
  float var = s2 * (1.0f / 1024.0f) - mu * mu;
  float rstd = rsqrtf(var + 1e-5f);
  float4 g = ((const float4*)gamma)[t];
  float4 be = ((const float4*)beta)[t];
  float4 y;
  y.x = (v.x - mu) * rstd * g.x + be.x;
  y.y = (v.y - mu) * rstd * g.y + be.y;
  y.z = (v.z - mu) * rstd * g.z + be.z;
  y.w = (v.w - mu) * rstd * g.w + be.w;
  ((float4*)(out + (size_t)row * 1024))[t] = y;
}

extern "C" void kernel_launch(void* const* d_in, const int* in_sizes, int n_in,
                              void* d_out, int out_size, void* d_ws, size_t ws_size,
                              hipStream_t stream) {
  const float* x     = (const float*)d_in[0];
  const float* Wq    = (const float*)d_in[1];
  const float* bq    = (const float*)d_in[2];
  const float* Wk    = (const float*)d_in[3];
  const float* bk    = (const float*)d_in[4];
  const float* Wv    = (const float*)d_in[5];
  const float* bv    = (const float*)d_in[6];
  const float* Wo    = (const float*)d_in[7];
  const float* bo    = (const float*)d_in[8];
  const float* gamma = (const float*)d_in[9];
  const float* beta  = (const float*)d_in[10];
  float* out = (float*)d_out;

  char* ws = (char*)d_ws;
  u16* xb   = (u16*)(ws);
  u16* Wt   = (u16*)(ws + ((size_t)8 << 20));
  u16* Qh   = (u16*)(ws + ((size_t)16 << 20));
  u16* Kh   = (u16*)(ws + ((size_t)24 << 20));
  u16* Vth  = (u16*)(ws + ((size_t)32 << 20));
  u16* ctx  = (u16*)(ws + ((size_t)40 << 20));
  float* aout = (float*)(ws + ((size_t)48 << 20));

  prep_kernel<<<8192, 256, 0, stream>>>(x, xb, Wq, Wk, Wv, Wo, Wt);
  qkv_gemm<<<dim3(32, 24), 256, 0, stream>>>(xb, Wt, bq, bk, bv, Qh, Kh, Vth);
  attn_kernel<<<dim3(32, 16), 512, 0, stream>>>(Qh, Kh, Vth, ctx);
  out_gemm<<<dim3(32, 16), 256, 0, stream>>>(ctx, Wt + (size_t)3 * 1024 * 1024, bo, aout);
  ln_kernel<<<4096, 256, 0, stream>>>(aout, x, gamma, beta, out);
}